// Round 7
// baseline (333.780 us; speedup 1.0000x reference)
//
#include <hip/hip_runtime.h>
#include <hip/hip_bf16.h>
#include <stdint.h>

#define NN 4096
#define NF 128

using f32x4  = __attribute__((ext_vector_type(4))) float;
using f32x16 = __attribute__((ext_vector_type(16))) float;
using bf16x8 = __attribute__((ext_vector_type(8))) __bf16;
using u16x8  = __attribute__((ext_vector_type(8))) uint16_t;
using i32x4  = __attribute__((ext_vector_type(4))) int;
using i32x8  = __attribute__((ext_vector_type(8))) int;

__device__ __forceinline__ uint16_t f2b(float f) {
    union { float f; uint32_t u; } v; v.f = f;
    uint32_t r = v.u + 0x7FFFu + ((v.u >> 16) & 1u);
    return (uint16_t)(r >> 16);
}

__device__ __forceinline__ uint32_t pk_fp8x4(float a, float b, float c, float d) {
    int p = __builtin_amdgcn_cvt_pk_fp8_f32(a, b, 0, false);
    p = __builtin_amdgcn_cvt_pk_fp8_f32(c, d, p, true);
    return (uint32_t)p;
}

__device__ __forceinline__ void gld_lds16(const void* g, void* l) {
    __builtin_amdgcn_global_load_lds(
        (const __attribute__((address_space(1))) uint32_t*)g,
        (__attribute__((address_space(3))) uint32_t*)l,
        16, 0, 0);
}

// ---------------------------------------------------------------------------
// Kernel 1: wc = W@a[:128], wr = W@a[128:] (fp32, for exact s via associativity)
// + WbT[f][k] = bf16(W[k][f])  (B^T operand for the XW GEMM)
// ---------------------------------------------------------------------------
__global__ __launch_bounds__(128) void wprep_kernel(
    const float* __restrict__ W, const float* __restrict__ a,
    float* __restrict__ wc, float* __restrict__ wr, uint16_t* __restrict__ WbT) {
    __shared__ float Wf[128 * 133];   // stride 133: 5k+f mod 32 -> conflict-free
    __shared__ float as[256];
    const int t = threadIdx.x;
    as[t] = a[t];
    as[128 + t] = a[128 + t];
    for (int j = 0; j < 128; ++j) Wf[j * 133 + t] = W[j * 128 + t];
    __syncthreads();
    float c = 0.f, r = 0.f;
    #pragma unroll 8
    for (int f = 0; f < 128; ++f) {
        float w = Wf[t * 133 + f];
        c += w * as[f];
        r += w * as[128 + f];
    }
    wc[t] = c; wr[t] = r;
    #pragma unroll 8
    for (int k = 0; k < 128; ++k)
        WbT[t * 128 + k] = f2b(Wf[k * 133 + t]);
}

// ---------------------------------------------------------------------------
// Kernel 2: s_col[i] = X[i]·wc, s_row[i] = X[i]·wr  (fp32-exact)
// ---------------------------------------------------------------------------
__global__ __launch_bounds__(256) void sxw_kernel(
    const float* __restrict__ X, const float* __restrict__ wc, const float* __restrict__ wr,
    float* __restrict__ s_col, float* __restrict__ s_row) {
    __shared__ float c_[NF], r_[NF];
    const int t = threadIdx.x;
    if (t < NF) c_[t] = wc[t]; else r_[t - NF] = wr[t - NF];
    __syncthreads();
    const int i = blockIdx.x * 256 + t;
    const float* xp = X + (size_t)i * NF;
    float sc = 0.f, sr = 0.f;
    #pragma unroll 8
    for (int k0 = 0; k0 < NF; k0 += 4) {
        float4 v = *(const float4*)(xp + k0);
        sc += v.x * c_[k0] + v.y * c_[k0 + 1] + v.z * c_[k0 + 2] + v.w * c_[k0 + 3];
        sr += v.x * r_[k0] + v.y * r_[k0 + 1] + v.z * r_[k0 + 2] + v.w * r_[k0 + 3];
    }
    s_col[i] = sc;
    s_row[i] = sr;
}

// ---------------------------------------------------------------------------
// Kernel 3: XWT[f][i] = bf16( (X@W)[i][f] ) — MFMA tile GEMM, K=128 resident.
// 32 blocks x 256 thr; LDS-transposed coalesced writes.
// ---------------------------------------------------------------------------
__global__ __launch_bounds__(256) void xwt_kernel(
    const float* __restrict__ X, const uint16_t* __restrict__ WbT,
    uint16_t* __restrict__ XWT) {
    __shared__ __align__(16) uint16_t Xs[128 * 136];
    __shared__ __align__(16) uint16_t Ws[128 * 136];
    const int tid = threadIdx.x, lane = tid & 63, wid = tid >> 6;
    const int wy = wid >> 1, wx = wid & 1;
    const int quad = lane >> 4, l16 = lane & 15;
    const int i0 = blockIdx.x * 128;
    {
        const int r = tid >> 1, h = tid & 1;
        const float* xp = X + (size_t)(i0 + r) * NF + h * 64;
        uint16_t* xd = Xs + r * 136 + h * 64;
        #pragma unroll
        for (int c = 0; c < 8; ++c) {
            float4 v0 = *(const float4*)(xp + c * 8);
            float4 v1 = *(const float4*)(xp + c * 8 + 4);
            u16x8 o;
            o[0] = f2b(v0.x); o[1] = f2b(v0.y); o[2] = f2b(v0.z); o[3] = f2b(v0.w);
            o[4] = f2b(v1.x); o[5] = f2b(v1.y); o[6] = f2b(v1.z); o[7] = f2b(v1.w);
            *(u16x8*)(xd + c * 8) = o;
        }
        const uint16_t* wp = WbT + r * 128 + h * 64;
        uint16_t* wd = Ws + r * 136 + h * 64;
        #pragma unroll
        for (int c = 0; c < 8; ++c)
            *(u16x8*)(wd + c * 8) = *(const u16x8*)(wp + c * 8);
    }
    __syncthreads();
    f32x4 acc[4][4];
    #pragma unroll
    for (int mi = 0; mi < 4; ++mi)
        #pragma unroll
        for (int ni = 0; ni < 4; ++ni)
            acc[mi][ni] = (f32x4){0.f, 0.f, 0.f, 0.f};
    #pragma unroll
    for (int kk = 0; kk < 4; ++kk) {
        const int k0 = kk * 32;
        bf16x8 af[4], bfr[4];
        #pragma unroll
        for (int mi = 0; mi < 4; ++mi)
            af[mi] = *(const bf16x8*)(Xs + (wy * 64 + mi * 16 + l16) * 136 + k0 + quad * 8);
        #pragma unroll
        for (int ni = 0; ni < 4; ++ni)
            bfr[ni] = *(const bf16x8*)(Ws + (wx * 64 + ni * 16 + l16) * 136 + k0 + quad * 8);
        #pragma unroll
        for (int mi = 0; mi < 4; ++mi)
            #pragma unroll
            for (int ni = 0; ni < 4; ++ni)
                acc[mi][ni] = __builtin_amdgcn_mfma_f32_16x16x32_bf16(af[mi], bfr[ni], acc[mi][ni], 0, 0, 0);
    }
    __syncthreads();
    // transpose via LDS (reuse Xs region): smemT[f][i_loc]
    #pragma unroll
    for (int mi = 0; mi < 4; ++mi)
        #pragma unroll
        for (int ni = 0; ni < 4; ++ni)
            #pragma unroll
            for (int r = 0; r < 4; ++r)
                Xs[(wx * 64 + ni * 16 + l16) * 136 + wy * 64 + mi * 16 + quad * 4 + r] =
                    f2b(acc[mi][ni][r]);
    __syncthreads();
    {
        const int f = tid >> 1, h = tid & 1;
        const u16x8* src = (const u16x8*)(Xs + f * 136 + h * 64);
        u16x8* dst = (u16x8*)(XWT + (size_t)f * NN + i0 + h * 64);
        #pragma unroll
        for (int c = 0; c < 8; ++c) dst[c] = src[c];
    }
}

// ---------------------------------------------------------------------------
// Kernel 4: A fp32 -> fp8-e4m3
// ---------------------------------------------------------------------------
__global__ void conv8_kernel(const float* __restrict__ in, uint32_t* __restrict__ o8) {
    int idx = blockIdx.x * blockDim.x + threadIdx.x;
    float4 v = ((const float4*)in)[idx];
    o8[idx] = pk_fp8x4(v.x, v.y, v.z, v.w);
}

// ---------------------------------------------------------------------------
// Kernel 5: denT8[j][k] = fp8(exp(leaky_relu(s_row[k] + s_col[j])))
// ---------------------------------------------------------------------------
__global__ void denT_kernel(const float* __restrict__ s_row, const float* __restrict__ s_col,
                            uint32_t* __restrict__ denT8) {
    int idx = blockIdx.x * blockDim.x + threadIdx.x;
    int j = idx >> 10;
    int k = (idx & 1023) << 2;
    float sc = s_col[j];
    float4 sr = *(const float4*)(s_row + k);
    float z0 = sc + sr.x; z0 = z0 > 0.f ? z0 : 0.01f * z0;
    float z1 = sc + sr.y; z1 = z1 > 0.f ? z1 : 0.01f * z1;
    float z2 = sc + sr.z; z2 = z2 > 0.f ? z2 : 0.01f * z2;
    float z3 = sc + sr.w; z3 = z3 > 0.f ? z3 : 0.01f * z3;
    denT8[idx] = pk_fp8x4(__expf(z0), __expf(z1), __expf(z2), __expf(z3));
}

// ---------------------------------------------------------------------------
// Kernel 6: num = A@den via MX-FP8 mfma_scale 32x32x64, fused att epilogue
// ---------------------------------------------------------------------------
__global__ __launch_bounds__(256) void gemm_att_kernel(
    const uint8_t* __restrict__ Ab8, const uint8_t* __restrict__ Bt8,
    const float* __restrict__ s_row, const float* __restrict__ s_col,
    uint16_t* __restrict__ att) {
    __shared__ __align__(16) char smem[128 * 272];
    char* As = smem;
    char* Bs = smem + 8192;
    const int bm0 = blockIdx.y * 128, bn0 = blockIdx.x * 128;

    const int tid  = threadIdx.x;
    const int lane = tid & 63;
    const int wid  = tid >> 6;
    const int wy   = wid >> 1, wx = wid & 1;
    const int m    = lane & 31, h = lane >> 5;

    const int sr_ = tid >> 2;
    const int scb = (((tid & 3) ^ ((sr_ >> 1) & 3)) << 4);

    f32x16 acc[2][2];
    #pragma unroll
    for (int mi = 0; mi < 2; ++mi)
        #pragma unroll
        for (int ni = 0; ni < 2; ++ni)
            #pragma unroll
            for (int r = 0; r < 16; ++r) acc[mi][ni][r] = 0.f;

    const int sw = (m >> 1) & 3;
    const int c0 = ((2 * h) ^ sw) << 4;
    const int c1 = ((2 * h + 1) ^ sw) << 4;

    for (int k0 = 0; k0 < NN; k0 += 64) {
        __syncthreads();
        gld_lds16(Ab8 + (size_t)(bm0 +      sr_) * NN + k0 + scb, As +        tid * 16);
        gld_lds16(Ab8 + (size_t)(bm0 + 64 + sr_) * NN + k0 + scb, As + 4096 + tid * 16);
        gld_lds16(Bt8 + (size_t)(bn0 +      sr_) * NN + k0 + scb, Bs +        tid * 16);
        gld_lds16(Bt8 + (size_t)(bn0 + 64 + sr_) * NN + k0 + scb, Bs + 4096 + tid * 16);
        __syncthreads();
        i32x8 af[2], bf[2];
        #pragma unroll
        for (int mi = 0; mi < 2; ++mi) {
            const char* p = As + (wy * 64 + mi * 32 + m) * 64;
            i32x4 lo = *(const i32x4*)(p + c0);
            i32x4 hi = *(const i32x4*)(p + c1);
            af[mi] = (i32x8){lo[0], lo[1], lo[2], lo[3], hi[0], hi[1], hi[2], hi[3]};
        }
        #pragma unroll
        for (int ni = 0; ni < 2; ++ni) {
            const char* p = Bs + (wx * 64 + ni * 32 + m) * 64;
            i32x4 lo = *(const i32x4*)(p + c0);
            i32x4 hi = *(const i32x4*)(p + c1);
            bf[ni] = (i32x8){lo[0], lo[1], lo[2], lo[3], hi[0], hi[1], hi[2], hi[3]};
        }
        #pragma unroll
        for (int mi = 0; mi < 2; ++mi)
            #pragma unroll
            for (int ni = 0; ni < 2; ++ni)
                acc[mi][ni] = __builtin_amdgcn_mfma_scale_f32_32x32x64_f8f6f4(
                    af[mi], bf[ni], acc[mi][ni], 0, 0,
                    0, 0x7F7F7F7F, 0, 0x7F7F7F7F);
    }

    __syncthreads();
    uint16_t* smem16 = (uint16_t*)smem;

    #pragma unroll
    for (int ni = 0; ni < 2; ++ni) {
        const int jl = wx * 64 + ni * 32 + m;
        const float scj = s_col[bn0 + jl];
        #pragma unroll
        for (int mi = 0; mi < 2; ++mi) {
            #pragma unroll
            for (int reg = 0; reg < 16; ++reg) {
                const int row = (reg & 3) + 8 * (reg >> 2) + 4 * h;
                const int il = wy * 64 + mi * 32 + row;
                float z = s_row[bm0 + il] + scj;
                z = z > 0.f ? z : 0.01f * z;
                const float den = __expf(z);
                const float num = acc[mi][ni][reg];
                float v = den * __builtin_amdgcn_rcpf(num);
                v = (num != 0.f) ? v : 0.f;
                smem16[il * 136 + jl] = f2b(v);
            }
        }
    }
    __syncthreads();
    {
        const int row = tid >> 1, half = tid & 1;
        const u16x8* src = (const u16x8*)(smem16 + row * 136 + half * 64);
        u16x8* dst = (u16x8*)(att + (size_t)(bm0 + row) * NN + bn0 + half * 64);
        #pragma unroll
        for (int c = 0; c < 8; ++c) dst[c] = src[c];
    }
}

// ---------------------------------------------------------------------------
// Kernel 7: P1[z][f][i] = sum_{k chunk} XWT[f][k]*att[i][k]  (M1^T partials)
// Wave-level, no LDS/barriers; att read exactly once; stores coalesced.
// Grid (256 i-tiles, 4 k-splits); 4 waves/block cover f 0..127.
// ---------------------------------------------------------------------------
__global__ __launch_bounds__(256) void wg1_kernel(
    const uint16_t* __restrict__ XWT, const uint16_t* __restrict__ att,
    float* __restrict__ P1) {
    const int tid = threadIdx.x, lane = tid & 63, w = tid >> 6;
    const int quad = lane >> 4, l16 = lane & 15;
    const int i0 = blockIdx.x * 16;
    const int f0 = w * 32;
    const int z  = blockIdx.y;
    const int kBeg = z * (NN / 4);

    const uint16_t* pa0 = XWT + (size_t)(f0 + l16)      * NN + kBeg + quad * 8;
    const uint16_t* pa1 = XWT + (size_t)(f0 + 16 + l16) * NN + kBeg + quad * 8;
    const uint16_t* pb  = att + (size_t)(i0 + l16)      * NN + kBeg + quad * 8;

    f32x4 acc[2] = {(f32x4){0,0,0,0}, (f32x4){0,0,0,0}};
    #pragma unroll 4
    for (int k = 0; k < NN / 4; k += 32) {
        bf16x8 a0 = *(const bf16x8*)(pa0 + k);
        bf16x8 a1 = *(const bf16x8*)(pa1 + k);
        bf16x8 b  = *(const bf16x8*)(pb  + k);
        acc[0] = __builtin_amdgcn_mfma_f32_16x16x32_bf16(a0, b, acc[0], 0, 0, 0);
        acc[1] = __builtin_amdgcn_mfma_f32_16x16x32_bf16(a1, b, acc[1], 0, 0, 0);
    }
    float* Pp = P1 + (size_t)z * (NF * NN);
    #pragma unroll
    for (int mi = 0; mi < 2; ++mi)
        #pragma unroll
        for (int r = 0; r < 4; ++r)
            Pp[(size_t)(f0 + mi * 16 + quad * 4 + r) * NN + i0 + l16] = acc[mi][r];
}

// ---------------------------------------------------------------------------
// Kernel 8: M1T[f][i] = bf16(sum_z P1[z][f][i])
// ---------------------------------------------------------------------------
__global__ void reduce1_kernel(const float* __restrict__ P1, uint16_t* __restrict__ M1T) {
    int idx = blockIdx.x * 256 + threadIdx.x;
    float s = 0.f;
    #pragma unroll
    for (int z = 0; z < 4; ++z) s += P1[(size_t)z * (NF * NN) + idx];
    M1T[idx] = f2b(s);
}

// ---------------------------------------------------------------------------
// Kernel 9: P2[z][i][f] = sum_{k chunk} A[i][k]*M1T[f][k]
// ---------------------------------------------------------------------------
__global__ __launch_bounds__(256) void wg2_kernel(
    const float* __restrict__ A, const uint16_t* __restrict__ M1T,
    float* __restrict__ P2) {
    const int tid = threadIdx.x, lane = tid & 63, w = tid >> 6;
    const int quad = lane >> 4, l16 = lane & 15;
    const int i0 = blockIdx.x * 16;
    const int f0 = w * 32;
    const int z  = blockIdx.y;
    const int kBeg = z * (NN / 4);

    const float*    pa  = A   + (size_t)(i0 + l16)      * NN + kBeg + quad * 8;
    const uint16_t* pb0 = M1T + (size_t)(f0 + l16)      * NN + kBeg + quad * 8;
    const uint16_t* pb1 = M1T + (size_t)(f0 + 16 + l16) * NN + kBeg + quad * 8;

    f32x4 acc[2] = {(f32x4){0,0,0,0}, (f32x4){0,0,0,0}};
    #pragma unroll 4
    for (int k = 0; k < NN / 4; k += 32) {
        float4 a0 = *(const float4*)(pa + k);
        float4 a1 = *(const float4*)(pa + k + 4);
        u16x8 au;
        au[0] = f2b(a0.x); au[1] = f2b(a0.y); au[2] = f2b(a0.z); au[3] = f2b(a0.w);
        au[4] = f2b(a1.x); au[5] = f2b(a1.y); au[6] = f2b(a1.z); au[7] = f2b(a1.w);
        bf16x8 af;
        __builtin_memcpy(&af, &au, 16);
        bf16x8 b0 = *(const bf16x8*)(pb0 + k);
        bf16x8 b1 = *(const bf16x8*)(pb1 + k);
        acc[0] = __builtin_amdgcn_mfma_f32_16x16x32_bf16(af, b0, acc[0], 0, 0, 0);
        acc[1] = __builtin_amdgcn_mfma_f32_16x16x32_bf16(af, b1, acc[1], 0, 0, 0);
    }
    float* Pp = P2 + (size_t)z * (NN * NF);
    #pragma unroll
    for (int ni = 0; ni < 2; ++ni)
        #pragma unroll
        for (int r = 0; r < 4; ++r)
            Pp[(size_t)(i0 + quad * 4 + r) * NF + f0 + ni * 16 + l16] = acc[ni][r];
}

// ---------------------------------------------------------------------------
// Kernel 10: H[i][f] = sum_z P2[z][i][f]
// ---------------------------------------------------------------------------
__global__ void reduce2_kernel(const float* __restrict__ P2, float* __restrict__ out) {
    int idx = blockIdx.x * 256 + threadIdx.x;
    float s = 0.f;
    #pragma unroll
    for (int z = 0; z < 4; ++z) s += P2[(size_t)z * (NN * NF) + idx];
    out[idx] = s;
}

// ---------------------------------------------------------------------------
extern "C" void kernel_launch(void* const* d_in, const int* in_sizes, int n_in,
                              void* d_out, int out_size, void* d_ws, size_t ws_size,
                              hipStream_t stream) {
    (void)in_sizes; (void)n_in; (void)out_size; (void)ws_size;
    const float* X = (const float*)d_in[0];
    const float* A = (const float*)d_in[1];
    const float* W = (const float*)d_in[2];
    const float* a = (const float*)d_in[3];
    float* H = (float*)d_out;

    char* ws = (char*)d_ws;
    uint32_t* denT8 = (uint32_t*)(ws);                          // 16 MB
    uint8_t*  Ab8   = (uint8_t*) (ws + ((size_t)16 << 20));     // 16 MB
    uint16_t* att   = (uint16_t*)(ws + ((size_t)32 << 20));     // 32 MB
    uint16_t* XWT   = (uint16_t*)(ws + ((size_t)64 << 20));     // 1 MB
    uint16_t* M1T   = (uint16_t*)(ws + ((size_t)65 << 20));     // 1 MB
    float*    s_col = (float*)   (ws + ((size_t)66 << 20));     // 16 KB
    float*    s_row = (float*)   (ws + ((size_t)66 << 20) + 16384);
    float*    P     = (float*)   (ws + ((size_t)67 << 20));     // 8 MB (P1 then P2)
    uint16_t* WbT   = (uint16_t*)(ws + ((size_t)76 << 20));     // 32 KB
    float*    wc    = (float*)   (ws + ((size_t)76 << 20) + 65536);
    float*    wr    = (float*)   (ws + ((size_t)76 << 20) + 66560);

    wprep_kernel<<<1, 128, 0, stream>>>(W, a, wc, wr, WbT);
    sxw_kernel<<<NN / 256, 256, 0, stream>>>(X, wc, wr, s_col, s_row);
    conv8_kernel<<<(NN * NN / 4) / 256, 256, 0, stream>>>(A, (uint32_t*)Ab8);
    denT_kernel<<<(NN * 1024) / 256, 256, 0, stream>>>(s_row, s_col, denT8);
    xwt_kernel<<<NN / 128, 256, 0, stream>>>(X, WbT, XWT);
    gemm_att_kernel<<<dim3(32, 32), 256, 0, stream>>>(Ab8, (const uint8_t*)denT8, s_row, s_col, att);
    wg1_kernel<<<dim3(256, 4), 256, 0, stream>>>(XWT, att, P);
    reduce1_kernel<<<(NF * NN) / 256, 256, 0, stream>>>(P, M1T);
    wg2_kernel<<<dim3(256, 4), 256, 0, stream>>>(A, M1T, P);
    reduce2_kernel<<<(NN * NF) / 256, 256, 0, stream>>>(P, H);
}

// Round 8
// 324.519 us; speedup vs baseline: 1.0285x; 1.0285x over previous
//
#include <hip/hip_runtime.h>
#include <hip/hip_bf16.h>
#include <stdint.h>

#define NN 4096
#define NF 128
#define NZ 8

using f32x4  = __attribute__((ext_vector_type(4))) float;
using f32x16 = __attribute__((ext_vector_type(16))) float;
using bf16x8 = __attribute__((ext_vector_type(8))) __bf16;
using u16x8  = __attribute__((ext_vector_type(8))) uint16_t;
using i32x4  = __attribute__((ext_vector_type(4))) int;
using i32x8  = __attribute__((ext_vector_type(8))) int;

__device__ __forceinline__ uint16_t f2b(float f) {
    union { float f; uint32_t u; } v; v.f = f;
    uint32_t r = v.u + 0x7FFFu + ((v.u >> 16) & 1u);
    return (uint16_t)(r >> 16);
}

__device__ __forceinline__ uint32_t pk_fp8x4(float a, float b, float c, float d) {
    int p = __builtin_amdgcn_cvt_pk_fp8_f32(a, b, 0, false);
    p = __builtin_amdgcn_cvt_pk_fp8_f32(c, d, p, true);
    return (uint32_t)p;
}

__device__ __forceinline__ void gld_lds16(const void* g, void* l) {
    __builtin_amdgcn_global_load_lds(
        (const __attribute__((address_space(1))) uint32_t*)g,
        (__attribute__((address_space(3))) uint32_t*)l,
        16, 0, 0);
}

// ---------------------------------------------------------------------------
// Kernel 1: XWT[f][i] = bf16((X@W)[i][f]) + s_col/s_row, all in one.
// 32 blocks x 256 thr. W loaded fp32 (coalesced) -> bf16 LDS transpose.
// s_col[i] = XW[i]·a[:128], s_row[i] = XW[i]·a[128:] from the LDS tile.
// ---------------------------------------------------------------------------
__global__ __launch_bounds__(256) void xwt_kernel(
    const float* __restrict__ X, const float* __restrict__ W,
    const float* __restrict__ a,
    uint16_t* __restrict__ XWT, float* __restrict__ s_col, float* __restrict__ s_row) {
    __shared__ __align__(16) uint16_t Xs[128 * 136];
    __shared__ __align__(16) uint16_t Ws[128 * 136];
    __shared__ float as[256];
    const int tid = threadIdx.x, lane = tid & 63, wid = tid >> 6;
    const int wy = wid >> 1, wx = wid & 1;
    const int quad = lane >> 4, l16 = lane & 15;
    const int i0 = blockIdx.x * 128;
    as[tid] = a[tid];
    {   // X tile -> bf16 LDS (row-major, stride 136)
        const int r = tid >> 1, h = tid & 1;
        const float* xp = X + (size_t)(i0 + r) * NF + h * 64;
        uint16_t* xd = Xs + r * 136 + h * 64;
        #pragma unroll
        for (int c = 0; c < 8; ++c) {
            float4 v0 = *(const float4*)(xp + c * 8);
            float4 v1 = *(const float4*)(xp + c * 8 + 4);
            u16x8 o;
            o[0] = f2b(v0.x); o[1] = f2b(v0.y); o[2] = f2b(v0.z); o[3] = f2b(v0.w);
            o[4] = f2b(v1.x); o[5] = f2b(v1.y); o[6] = f2b(v1.z); o[7] = f2b(v1.w);
            *(u16x8*)(xd + c * 8) = o;
        }
    }
    {   // W transpose -> Ws[f][k] bf16 (coalesced global reads)
        const int f = tid & 127, kh = tid >> 7;
        for (int k = kh; k < 128; k += 2)
            Ws[f * 136 + k] = f2b(W[k * NF + f]);
    }
    __syncthreads();
    f32x4 acc[4][4];
    #pragma unroll
    for (int mi = 0; mi < 4; ++mi)
        #pragma unroll
        for (int ni = 0; ni < 4; ++ni)
            acc[mi][ni] = (f32x4){0.f, 0.f, 0.f, 0.f};
    #pragma unroll
    for (int kk = 0; kk < 4; ++kk) {
        const int k0 = kk * 32;
        bf16x8 af[4], bfr[4];
        #pragma unroll
        for (int mi = 0; mi < 4; ++mi)
            af[mi] = *(const bf16x8*)(Xs + (wy * 64 + mi * 16 + l16) * 136 + k0 + quad * 8);
        #pragma unroll
        for (int ni = 0; ni < 4; ++ni)
            bfr[ni] = *(const bf16x8*)(Ws + (wx * 64 + ni * 16 + l16) * 136 + k0 + quad * 8);
        #pragma unroll
        for (int mi = 0; mi < 4; ++mi)
            #pragma unroll
            for (int ni = 0; ni < 4; ++ni)
                acc[mi][ni] = __builtin_amdgcn_mfma_f32_16x16x32_bf16(af[mi], bfr[ni], acc[mi][ni], 0, 0, 0);
    }
    __syncthreads();
    // transpose result into Xs: Xs[f][i_loc]
    #pragma unroll
    for (int mi = 0; mi < 4; ++mi)
        #pragma unroll
        for (int ni = 0; ni < 4; ++ni)
            #pragma unroll
            for (int r = 0; r < 4; ++r)
                Xs[(wx * 64 + ni * 16 + l16) * 136 + wy * 64 + mi * 16 + quad * 4 + r] =
                    f2b(acc[mi][ni][r]);
    __syncthreads();
    {   // coalesced XWT stores
        const int f = tid >> 1, h = tid & 1;
        const u16x8* src = (const u16x8*)(Xs + f * 136 + h * 64);
        u16x8* dst = (u16x8*)(XWT + (size_t)f * NN + i0 + h * 64);
        #pragma unroll
        for (int c = 0; c < 8; ++c) dst[c] = src[c];
    }
    {   // s_col (tid<128) / s_row (tid>=128) from the bf16 tile
        const int which = tid >> 7;
        const int i = tid & 127;
        float s = 0.f;
        #pragma unroll 8
        for (int f = 0; f < 128; ++f) {
            float xw = (float)*(const __bf16*)(Xs + f * 136 + i);
            s += xw * as[which * 128 + f];
        }
        if (which == 0) s_col[i0 + i] = s; else s_row[i0 + i] = s;
    }
}

// ---------------------------------------------------------------------------
// Kernel 2 (fused): blocks [0,16384): A fp32 -> fp8;
//                   blocks [16384,32768): denT8[j][k] = fp8(exp(lr(sr[k]+sc[j])))
// ---------------------------------------------------------------------------
__global__ void convden_kernel(const float* __restrict__ A, uint32_t* __restrict__ Ab8,
                               const float* __restrict__ s_row, const float* __restrict__ s_col,
                               uint32_t* __restrict__ denT8) {
    const int b = blockIdx.x;
    if (b < 16384) {
        int idx = b * 256 + threadIdx.x;
        float4 v = ((const float4*)A)[idx];
        Ab8[idx] = pk_fp8x4(v.x, v.y, v.z, v.w);
    } else {
        int idx = (b - 16384) * 256 + threadIdx.x;
        int j = idx >> 10;
        int k = (idx & 1023) << 2;
        float sc = s_col[j];
        float4 sr = *(const float4*)(s_row + k);
        float z0 = sc + sr.x; z0 = z0 > 0.f ? z0 : 0.01f * z0;
        float z1 = sc + sr.y; z1 = z1 > 0.f ? z1 : 0.01f * z1;
        float z2 = sc + sr.z; z2 = z2 > 0.f ? z2 : 0.01f * z2;
        float z3 = sc + sr.w; z3 = z3 > 0.f ? z3 : 0.01f * z3;
        denT8[idx] = pk_fp8x4(__expf(z0), __expf(z1), __expf(z2), __expf(z3));
    }
}

// ---------------------------------------------------------------------------
// Kernel 3: num = A@den via MX-FP8 mfma_scale 32x32x64, fused att epilogue
// (unchanged from R3 — known 104 µs)
// ---------------------------------------------------------------------------
__global__ __launch_bounds__(256) void gemm_att_kernel(
    const uint8_t* __restrict__ Ab8, const uint8_t* __restrict__ Bt8,
    const float* __restrict__ s_row, const float* __restrict__ s_col,
    uint16_t* __restrict__ att) {
    __shared__ __align__(16) char smem[128 * 272];
    char* As = smem;
    char* Bs = smem + 8192;
    const int bm0 = blockIdx.y * 128, bn0 = blockIdx.x * 128;

    const int tid  = threadIdx.x;
    const int lane = tid & 63;
    const int wid  = tid >> 6;
    const int wy   = wid >> 1, wx = wid & 1;
    const int m    = lane & 31, h = lane >> 5;

    const int sr_ = tid >> 2;
    const int scb = (((tid & 3) ^ ((sr_ >> 1) & 3)) << 4);

    f32x16 acc[2][2];
    #pragma unroll
    for (int mi = 0; mi < 2; ++mi)
        #pragma unroll
        for (int ni = 0; ni < 2; ++ni)
            #pragma unroll
            for (int r = 0; r < 16; ++r) acc[mi][ni][r] = 0.f;

    const int sw = (m >> 1) & 3;
    const int c0 = ((2 * h) ^ sw) << 4;
    const int c1 = ((2 * h + 1) ^ sw) << 4;

    for (int k0 = 0; k0 < NN; k0 += 64) {
        __syncthreads();
        gld_lds16(Ab8 + (size_t)(bm0 +      sr_) * NN + k0 + scb, As +        tid * 16);
        gld_lds16(Ab8 + (size_t)(bm0 + 64 + sr_) * NN + k0 + scb, As + 4096 + tid * 16);
        gld_lds16(Bt8 + (size_t)(bn0 +      sr_) * NN + k0 + scb, Bs +        tid * 16);
        gld_lds16(Bt8 + (size_t)(bn0 + 64 + sr_) * NN + k0 + scb, Bs + 4096 + tid * 16);
        __syncthreads();
        i32x8 af[2], bf[2];
        #pragma unroll
        for (int mi = 0; mi < 2; ++mi) {
            const char* p = As + (wy * 64 + mi * 32 + m) * 64;
            i32x4 lo = *(const i32x4*)(p + c0);
            i32x4 hi = *(const i32x4*)(p + c1);
            af[mi] = (i32x8){lo[0], lo[1], lo[2], lo[3], hi[0], hi[1], hi[2], hi[3]};
        }
        #pragma unroll
        for (int ni = 0; ni < 2; ++ni) {
            const char* p = Bs + (wx * 64 + ni * 32 + m) * 64;
            i32x4 lo = *(const i32x4*)(p + c0);
            i32x4 hi = *(const i32x4*)(p + c1);
            bf[ni] = (i32x8){lo[0], lo[1], lo[2], lo[3], hi[0], hi[1], hi[2], hi[3]};
        }
        #pragma unroll
        for (int mi = 0; mi < 2; ++mi)
            #pragma unroll
            for (int ni = 0; ni < 2; ++ni)
                acc[mi][ni] = __builtin_amdgcn_mfma_scale_f32_32x32x64_f8f6f4(
                    af[mi], bf[ni], acc[mi][ni], 0, 0,
                    0, 0x7F7F7F7F, 0, 0x7F7F7F7F);
    }

    __syncthreads();
    uint16_t* smem16 = (uint16_t*)smem;

    #pragma unroll
    for (int ni = 0; ni < 2; ++ni) {
        const int jl = wx * 64 + ni * 32 + m;
        const float scj = s_col[bn0 + jl];
        #pragma unroll
        for (int mi = 0; mi < 2; ++mi) {
            #pragma unroll
            for (int reg = 0; reg < 16; ++reg) {
                const int row = (reg & 3) + 8 * (reg >> 2) + 4 * h;
                const int il = wy * 64 + mi * 32 + row;
                float z = s_row[bm0 + il] + scj;
                z = z > 0.f ? z : 0.01f * z;
                const float den = __expf(z);
                const float num = acc[mi][ni][reg];
                float v = den * __builtin_amdgcn_rcpf(num);
                v = (num != 0.f) ? v : 0.f;
                smem16[il * 136 + jl] = f2b(v);
            }
        }
    }
    __syncthreads();
    {
        const int row = tid >> 1, half = tid & 1;
        const u16x8* src = (const u16x8*)(smem16 + row * 136 + half * 64);
        u16x8* dst = (u16x8*)(att + (size_t)(bm0 + row) * NN + bn0 + half * 64);
        #pragma unroll
        for (int c = 0; c < 8; ++c) dst[c] = src[c];
    }
}

// ---------------------------------------------------------------------------
// Kernel 4: P1[z][f][i] = sum_{k chunk} XWT[f][k]*att[i][k]  (M1^T partials)
// Wave-level, no LDS/barriers; z=8 -> 2048 blocks = 32 waves/CU.
// ---------------------------------------------------------------------------
__global__ __launch_bounds__(256) void wg1_kernel(
    const uint16_t* __restrict__ XWT, const uint16_t* __restrict__ att,
    float* __restrict__ P1) {
    const int tid = threadIdx.x, lane = tid & 63, w = tid >> 6;
    const int quad = lane >> 4, l16 = lane & 15;
    const int i0 = blockIdx.x * 16;
    const int f0 = w * 32;
    const int z  = blockIdx.y;
    const int kBeg = z * (NN / NZ);

    const uint16_t* pa0 = XWT + (size_t)(f0 + l16)      * NN + kBeg + quad * 8;
    const uint16_t* pa1 = XWT + (size_t)(f0 + 16 + l16) * NN + kBeg + quad * 8;
    const uint16_t* pb  = att + (size_t)(i0 + l16)      * NN + kBeg + quad * 8;

    f32x4 acc[2] = {(f32x4){0,0,0,0}, (f32x4){0,0,0,0}};
    #pragma unroll 4
    for (int k = 0; k < NN / NZ; k += 32) {
        bf16x8 a0 = *(const bf16x8*)(pa0 + k);
        bf16x8 a1 = *(const bf16x8*)(pa1 + k);
        bf16x8 b  = *(const bf16x8*)(pb  + k);
        acc[0] = __builtin_amdgcn_mfma_f32_16x16x32_bf16(a0, b, acc[0], 0, 0, 0);
        acc[1] = __builtin_amdgcn_mfma_f32_16x16x32_bf16(a1, b, acc[1], 0, 0, 0);
    }
    float* Pp = P1 + (size_t)z * (NF * NN);
    #pragma unroll
    for (int mi = 0; mi < 2; ++mi)
        #pragma unroll
        for (int r = 0; r < 4; ++r)
            Pp[(size_t)(f0 + mi * 16 + quad * 4 + r) * NN + i0 + l16] = acc[mi][r];
}

// ---------------------------------------------------------------------------
// Kernel 5: M1T[f][i] = bf16(sum_z P1[z][f][i])
// ---------------------------------------------------------------------------
__global__ void reduce1_kernel(const float* __restrict__ P1, uint16_t* __restrict__ M1T) {
    int idx = blockIdx.x * 256 + threadIdx.x;
    float s = 0.f;
    #pragma unroll
    for (int z = 0; z < NZ; ++z) s += P1[(size_t)z * (NF * NN) + idx];
    M1T[idx] = f2b(s);
}

// ---------------------------------------------------------------------------
// Kernel 6: P2[z][i][f] = sum_{k chunk} A[i][k]*M1T[f][k]
// ---------------------------------------------------------------------------
__global__ __launch_bounds__(256) void wg2_kernel(
    const float* __restrict__ A, const uint16_t* __restrict__ M1T,
    float* __restrict__ P2) {
    const int tid = threadIdx.x, lane = tid & 63, w = tid >> 6;
    const int quad = lane >> 4, l16 = lane & 15;
    const int i0 = blockIdx.x * 16;
    const int f0 = w * 32;
    const int z  = blockIdx.y;
    const int kBeg = z * (NN / NZ);

    const float*    pa  = A   + (size_t)(i0 + l16)      * NN + kBeg + quad * 8;
    const uint16_t* pb0 = M1T + (size_t)(f0 + l16)      * NN + kBeg + quad * 8;
    const uint16_t* pb1 = M1T + (size_t)(f0 + 16 + l16) * NN + kBeg + quad * 8;

    f32x4 acc[2] = {(f32x4){0,0,0,0}, (f32x4){0,0,0,0}};
    #pragma unroll 4
    for (int k = 0; k < NN / NZ; k += 32) {
        float4 a0 = *(const float4*)(pa + k);
        float4 a1 = *(const float4*)(pa + k + 4);
        u16x8 au;
        au[0] = f2b(a0.x); au[1] = f2b(a0.y); au[2] = f2b(a0.z); au[3] = f2b(a0.w);
        au[4] = f2b(a1.x); au[5] = f2b(a1.y); au[6] = f2b(a1.z); au[7] = f2b(a1.w);
        bf16x8 af;
        __builtin_memcpy(&af, &au, 16);
        bf16x8 b0 = *(const bf16x8*)(pb0 + k);
        bf16x8 b1 = *(const bf16x8*)(pb1 + k);
        acc[0] = __builtin_amdgcn_mfma_f32_16x16x32_bf16(af, b0, acc[0], 0, 0, 0);
        acc[1] = __builtin_amdgcn_mfma_f32_16x16x32_bf16(af, b1, acc[1], 0, 0, 0);
    }
    float* Pp = P2 + (size_t)z * (NN * NF);
    #pragma unroll
    for (int ni = 0; ni < 2; ++ni)
        #pragma unroll
        for (int r = 0; r < 4; ++r)
            Pp[(size_t)(i0 + quad * 4 + r) * NF + f0 + ni * 16 + l16] = acc[ni][r];
}

// ---------------------------------------------------------------------------
// Kernel 7: H[i][f] = sum_z P2[z][i][f]
// ---------------------------------------------------------------------------
__global__ void reduce2_kernel(const float* __restrict__ P2, float* __restrict__ out) {
    int idx = blockIdx.x * 256 + threadIdx.x;
    float s = 0.f;
    #pragma unroll
    for (int z = 0; z < NZ; ++z) s += P2[(size_t)z * (NN * NF) + idx];
    out[idx] = s;
}

// ---------------------------------------------------------------------------
extern "C" void kernel_launch(void* const* d_in, const int* in_sizes, int n_in,
                              void* d_out, int out_size, void* d_ws, size_t ws_size,
                              hipStream_t stream) {
    (void)in_sizes; (void)n_in; (void)out_size; (void)ws_size;
    const float* X = (const float*)d_in[0];
    const float* A = (const float*)d_in[1];
    const float* W = (const float*)d_in[2];
    const float* a = (const float*)d_in[3];
    float* H = (float*)d_out;

    char* ws = (char*)d_ws;
    uint32_t* denT8 = (uint32_t*)(ws);                          // 16 MB
    uint8_t*  Ab8   = (uint8_t*) (ws + ((size_t)16 << 20));     // 16 MB
    uint16_t* att   = (uint16_t*)(ws + ((size_t)32 << 20));     // 32 MB
    uint16_t* XWT   = (uint16_t*)(ws + ((size_t)64 << 20));     // 1 MB
    uint16_t* M1T   = (uint16_t*)(ws + ((size_t)65 << 20));     // 1 MB
    float*    s_col = (float*)   (ws + ((size_t)66 << 20));     // 16 KB
    float*    s_row = (float*)   (ws + ((size_t)66 << 20) + 16384);
    float*    P     = (float*)   (ws + ((size_t)67 << 20));     // 16 MB (P1 then P2)

    xwt_kernel<<<NN / 128, 256, 0, stream>>>(X, W, a, XWT, s_col, s_row);
    convden_kernel<<<32768, 256, 0, stream>>>(A, (uint32_t*)Ab8, s_row, s_col, denT8);
    gemm_att_kernel<<<dim3(32, 32), 256, 0, stream>>>(Ab8, (const uint8_t*)denT8, s_row, s_col, att);
    wg1_kernel<<<dim3(256, NZ), 256, 0, stream>>>(XWT, att, P);
    reduce1_kernel<<<(NF * NN) / 256, 256, 0, stream>>>(P, M1T);
    wg2_kernel<<<dim3(256, NZ), 256, 0, stream>>>(A, M1T, P);
    reduce2_kernel<<<(NN * NF) / 256, 256, 0, stream>>>(P, H);
}